// Round 8
// baseline (89.955 us; speedup 1.0000x reference)
//
#include <hip/hip_runtime.h>
#include <math.h>

// Chamfer one-sided NN distance sum. N = M = 16384, D = 3, fp32 -> scalar fp32.
//
// MFMA formulation: d2(i,j) = |a_i|^2 + |b_j|^2 - 2 a_i.b_j computed entirely
// inside one v_mfma_f32_32x32x16_bf16 per 32x32 tile via split-bf16 packing:
//   A[i][k] = [ahx,ahy,ahz, ahx,ahy,ahz, alx,aly,alz, alx,aly,alz, a2h,a2l, 1,1]
//   B[j][k] = [-2bhx,-2bhy,-2bhz, -2blx,-2bly,-2blz,
//              -2bhx,-2bhy,-2bhz, -2blx,-2bly,-2blz, 1,1, b2h,b2l]
//   sum_k A_k B_k = a2 + b2 - 2(ah+al).(bh+bl)   (bf16 products exact in fp32;
//   split residual ~2^-18 -> d2 error ~1e-4, final-sum error << 32.8 threshold)
// fp32 VALU floor for this problem is ~12 us (v_pk_fma_f32 is half-rate per
// component on gfx950 — 157.3 TF spec is scalar-saturated); MFMA pipe does the
// same pairs in ~1 us, leaving an L2-traffic bound (~7.4 us).
//
// k_prep: packs apack/bpack (512 KB each) into ws, zeroes out[0].
// k_pair: 512 blocks = one 32-row a-tile each; 4 waves = 4 b-quarters
//   (128 tiles each). Fragment loads: lane holds row/col = lane&31,
//   k-half = lane>>5 -> one dwordx4, wave's 64 loads tile 1 KB contiguously.
//   acc seeded with a zero 16-vector (compiler keeps one zeroed tuple);
//   2 tiles per min3 group: best = min3(c0[r], c1[r], best) = 8 VALU/tile.
//   Epilogue: LDS atomicMin (fp32 bits, values >= 0 monotone as int) over
//   rows, sqrt, wave-0 butterfly sum, one atomicAdd per block.
//   C/D layout (m74/m101): col = lane&31, row = (reg&3)+8*(reg>>2)+4*(lane>>5).

#define NPTS 16384

typedef short s16x8 __attribute__((ext_vector_type(8)));
typedef float f32x16 __attribute__((ext_vector_type(16)));

__device__ __forceinline__ unsigned short f2bf(float x) {
    unsigned u = __float_as_uint(x);
    u = u + 0x7FFFu + ((u >> 16) & 1u);   // RNE
    return (unsigned short)(u >> 16);
}
__device__ __forceinline__ float bf2f(unsigned short h) {
    return __uint_as_float((unsigned)h << 16);
}

__global__ __launch_bounds__(256)
void cd_prep_kernel(const float* __restrict__ a, const float* __restrict__ b,
                    unsigned short* __restrict__ apack,
                    unsigned short* __restrict__ bpack,
                    float* __restrict__ out) {
    const int i = blockIdx.x * 256 + threadIdx.x;     // 0 .. 2*NPTS-1
    if (i == 0) out[0] = 0.0f;                        // pair kernel ordered after
    const bool isA = i < NPTS;
    const int p = isA ? i : i - NPTS;
    const float* src = isA ? a : b;
    const float x = src[3 * p + 0];
    const float y = src[3 * p + 1];
    const float z = src[3 * p + 2];
    const float n2 = fmaf(x, x, fmaf(y, y, z * z));

    const unsigned short hx = f2bf(x), hy = f2bf(y), hz = f2bf(z);
    const unsigned short lx = f2bf(x - bf2f(hx));
    const unsigned short ly = f2bf(y - bf2f(hy));
    const unsigned short lz = f2bf(z - bf2f(hz));
    const unsigned short n2h = f2bf(n2);
    const unsigned short n2l = f2bf(n2 - bf2f(n2h));
    const unsigned short one = f2bf(1.0f);

    if (isA) {
        unsigned short* o = apack + p * 16;
        o[0] = hx;  o[1] = hy;  o[2] = hz;  o[3] = hx;  o[4] = hy;  o[5] = hz;
        o[6] = lx;  o[7] = ly;  o[8] = lz;  o[9] = lx;  o[10] = ly; o[11] = lz;
        o[12] = n2h; o[13] = n2l; o[14] = one; o[15] = one;
    } else {
        // -2*bf16 values are exact (power-of-two scale + negate)
        const unsigned short thx = f2bf(-2.0f * bf2f(hx));
        const unsigned short thy = f2bf(-2.0f * bf2f(hy));
        const unsigned short thz = f2bf(-2.0f * bf2f(hz));
        const unsigned short tlx = f2bf(-2.0f * bf2f(lx));
        const unsigned short tly = f2bf(-2.0f * bf2f(ly));
        const unsigned short tlz = f2bf(-2.0f * bf2f(lz));
        unsigned short* o = bpack + p * 16;
        o[0] = thx; o[1] = thy; o[2] = thz; o[3] = tlx; o[4] = tly; o[5] = tlz;
        o[6] = thx; o[7] = thy; o[8] = thz; o[9] = tlx; o[10] = tly; o[11] = tlz;
        o[12] = one; o[13] = one; o[14] = n2h; o[15] = n2l;
    }
}

__global__ __launch_bounds__(256)
void cd_pair_kernel(const unsigned short* __restrict__ apack,
                    const unsigned short* __restrict__ bpack,
                    float* __restrict__ out) {
    __shared__ int rowmin[32];
    const int tid = threadIdx.x;
    if (tid < 32) rowmin[tid] = 0x7F800000;           // +inf bits
    __syncthreads();

    const int lane  = tid & 63;
    const int wave  = tid >> 6;                       // b-quarter 0..3
    const int col   = lane & 31;
    const int khalf = lane >> 5;                      // k in [8*khalf, 8*khalf+8)

    // A fragment: row = blockIdx.x*32 + col, constant over the loop
    const int arow = blockIdx.x * 32 + col;
    const s16x8 afrag = *(const s16x8*)(apack + (size_t)arow * 16 + khalf * 8);

    // B fragment base for this wave's quarter
    const unsigned short* bp =
        bpack + ((size_t)(wave * 4096 + col) * 16 + khalf * 8);

    f32x16 best, zero;
    #pragma unroll
    for (int r = 0; r < 16; ++r) { best[r] = 3.4028235e38f; zero[r] = 0.0f; }

    #pragma unroll 2
    for (int t = 0; t < 128; t += 2) {                // 128 tiles of 32 b-points
        const s16x8 b0 = *(const s16x8*)(bp + (size_t)t * 512);
        const s16x8 b1 = *(const s16x8*)(bp + (size_t)t * 512 + 512);
        const f32x16 c0 = __builtin_amdgcn_mfma_f32_32x32x16_bf16(afrag, b0, zero, 0, 0, 0);
        const f32x16 c1 = __builtin_amdgcn_mfma_f32_32x32x16_bf16(afrag, b1, zero, 0, 0, 0);
        #pragma unroll
        for (int r = 0; r < 16; ++r)
            best[r] = fminf(fminf(c0[r], c1[r]), best[r]);  // v_min3_f32
    }

    // merge: lane's 16 regs are 16 rows (fixed col); d2 >= 0 -> int-min on bits
    #pragma unroll
    for (int r = 0; r < 16; ++r) {
        const int row = (r & 3) + 8 * (r >> 2) + 4 * khalf;
        atomicMin(&rowmin[row], __float_as_int(best[r]));
    }
    __syncthreads();

    if (tid < 64) {                                   // wave 0 only
        float d = 0.0f;
        if (tid < 32) d = sqrtf(fmaxf(__int_as_float(rowmin[tid]), 0.0f));
        for (int off = 32; off > 0; off >>= 1)
            d += __shfl_down(d, off, 64);
        if (tid == 0) atomicAdd(out, d);
    }
}

extern "C" void kernel_launch(void* const* d_in, const int* in_sizes, int n_in,
                              void* d_out, int out_size, void* d_ws, size_t ws_size,
                              hipStream_t stream) {
    const float* a = (const float*)d_in[0];
    const float* b = (const float*)d_in[1];
    float* out = (float*)d_out;
    unsigned short* apack = (unsigned short*)d_ws;          // NPTS*16 u16 = 512 KB
    unsigned short* bpack = apack + (size_t)NPTS * 16;      // + 512 KB

    cd_prep_kernel<<<(2 * NPTS) / 256, 256, 0, stream>>>(a, b, apack, bpack, out);
    cd_pair_kernel<<<NPTS / 32, 256, 0, stream>>>(apack, bpack, out);
}